// Round 7
// baseline (2420.050 us; speedup 1.0000x reference)
//
#include <hip/hip_runtime.h>

// Round 16 (resubmit — never ran: GPUAcquisitionTimeout, no counters).
// Attack LDS instruction bandwidth, not the schedule. Evidence:
// r13/r14/r15 (three different schedules) all = 208-213us, VALUBusy pinned at
// 67%. Model: 8x8/thread needs 4 ds_read_b128 (48 LDS-pipe cyc/wave) per
// 64 FMA (128 VALU cyc/SIMD); per CU LDS demand/VALU = 192w/128w = 1.5 ->
// FMA duty capped at 67% = measured VALUBusy. Schedule-invariant.
// Change: 16x8 out/thread, tile 256x128, 256 threads. Per k-step 6 b128 for
// 128 FMA -> LDS:VALU = 288w/256w = 1.125. acc=128 VGPR, total ~190 ->
// __launch_bounds__(256,2) (cap 256, margin >60 regs, r12's spill was cap <
// need). Grid 8x16x4=512 = 2 blocks/CU. LDS 50KB dbuf (r14 single-barrier
// structure kept). Bit-exact: same serial k-ascending FMA per element, same
// 512-k chunks, ordered reduce unchanged -> absmax 0.0.
// Tripwire: WRITE_SIZE must stay 65536 KB (spill would balloon it).

#define NMAT 2048

constexpr int FK = 16;      // k-depth per LDS tile
constexpr int KCHUNK = 512; // flush granularity (bit-exact)
// split-K kernel tile: 256 (M) x 128 (N), 256 threads, 16x8 per thread
constexpr int CM = 256, CN = 128;
constexpr int LDA2 = CM + 4; // 260 floats; 260*4=1040=16*65 -> b128-aligned
constexpr int LDB2 = CN + 4; // 132 floats; 528=16*33 -> b128-aligned

// ---------- split-K chunk kernel: acc over k in [z*512, (z+1)*512) ----------
__global__ __launch_bounds__(256, 2) void sgemm_chunk(
    const float* __restrict__ Am, const float* __restrict__ Bm,
    float* __restrict__ Pm) {
  __shared__ float As[2][FK][LDA2]; // [buf][k][m] 33280 B
  __shared__ float Bs[2][FK][LDB2]; // [buf][k][n] 16896 B
  const int tid = threadIdx.x;
  const int row0 = blockIdx.y * CM;
  const int col0 = blockIdx.x * CN;
  const int kb = blockIdx.z * KCHUNK;
  const int ty = tid >> 4; // 0..15 -> rows ty*4 + {0..3} + 64q, q=0..3
  const int tx = tid & 15; // 0..15 -> cols tx*4 + {0..3} + 64g, g=0..1

  // staging indices
  const int ar = tid >> 2;      // 0..63  (A passes: +0,+64,+128,+192)
  const int ac = (tid & 3) * 4; // 0,4,8,12 (k-offset within tile)
  const int bk = tid >> 5;      // 0..7   (B passes: +0,+8)
  const int bc = (tid & 31) * 4;

  float acc[16][8] = {};
  float4 va[4], vb[2];

  const float* pa = &Am[(size_t)(row0 + ar) * NMAT + kb + ac];
  const float* pb = &Bm[(size_t)(kb + bk) * NMAT + col0 + bc];

  constexpr int NT = KCHUNK / FK; // 32 tiles

  // prologue: tile 0 -> buf 0
#pragma unroll
  for (int p = 0; p < 4; ++p)
    va[p] = *(const float4*)(pa + (size_t)(64 * p) * NMAT);
#pragma unroll
  for (int p = 0; p < 2; ++p)
    vb[p] = *(const float4*)(pb + (size_t)(8 * p) * NMAT);
#pragma unroll
  for (int p = 0; p < 4; ++p) {
    As[0][ac + 0][ar + 64 * p] = va[p].x;
    As[0][ac + 1][ar + 64 * p] = va[p].y;
    As[0][ac + 2][ar + 64 * p] = va[p].z;
    As[0][ac + 3][ar + 64 * p] = va[p].w;
  }
#pragma unroll
  for (int p = 0; p < 2; ++p)
    *(float4*)&Bs[0][bk + 8 * p][bc] = vb[p];
  // tile 1 -> registers
  pa += FK;
  pb += (size_t)FK * NMAT;
#pragma unroll
  for (int p = 0; p < 4; ++p)
    va[p] = *(const float4*)(pa + (size_t)(64 * p) * NMAT);
#pragma unroll
  for (int p = 0; p < 2; ++p)
    vb[p] = *(const float4*)(pb + (size_t)(8 * p) * NMAT);
  __syncthreads();

#pragma unroll 1
  for (int t = 0; t < NT; ++t) {
    const int cur = t & 1;
    const int nxt = cur ^ 1;

    // store tile t+1 (in regs) into the other buffer — overlaps with FMA
    if (t + 1 < NT) {
#pragma unroll
      for (int p = 0; p < 4; ++p) {
        As[nxt][ac + 0][ar + 64 * p] = va[p].x;
        As[nxt][ac + 1][ar + 64 * p] = va[p].y;
        As[nxt][ac + 2][ar + 64 * p] = va[p].z;
        As[nxt][ac + 3][ar + 64 * p] = va[p].w;
      }
#pragma unroll
      for (int p = 0; p < 2; ++p)
        *(float4*)&Bs[nxt][bk + 8 * p][bc] = vb[p];
    }
    // issue global loads for tile t+2 — latency hidden under FMA block
    if (t + 2 < NT) {
      pa += FK;
      pb += (size_t)FK * NMAT;
#pragma unroll
      for (int p = 0; p < 4; ++p)
        va[p] = *(const float4*)(pa + (size_t)(64 * p) * NMAT);
#pragma unroll
      for (int p = 0; p < 2; ++p)
        vb[p] = *(const float4*)(pb + (size_t)(8 * p) * NMAT);
    }

    // compute: 16 k-steps, serial k-ascending per element (bit-exact order)
#pragma unroll
    for (int k = 0; k < FK; ++k) {
      float4 a0 = *(const float4*)&As[cur][k][ty * 4];
      float4 a1 = *(const float4*)&As[cur][k][64 + ty * 4];
      float4 a2 = *(const float4*)&As[cur][k][128 + ty * 4];
      float4 a3 = *(const float4*)&As[cur][k][192 + ty * 4];
      float4 b0 = *(const float4*)&Bs[cur][k][tx * 4];
      float4 b1 = *(const float4*)&Bs[cur][k][64 + tx * 4];
      const float af[16] = {a0.x, a0.y, a0.z, a0.w, a1.x, a1.y, a1.z, a1.w,
                            a2.x, a2.y, a2.z, a2.w, a3.x, a3.y, a3.z, a3.w};
      const float bf[8] = {b0.x, b0.y, b0.z, b0.w, b1.x, b1.y, b1.z, b1.w};
#pragma unroll
      for (int i = 0; i < 16; ++i)
#pragma unroll
        for (int j = 0; j < 8; ++j)
          acc[i][j] = fmaf(af[i], bf[j], acc[i][j]);
    }
    __syncthreads(); // buf[nxt] complete; buf[cur] free for reuse
  }

  // write raw chunk accumulator to partial slab z
  float* dst = Pm + (size_t)blockIdx.z * NMAT * NMAT;
#pragma unroll
  for (int i = 0; i < 16; ++i) {
    const int r = row0 + (i >> 2) * 64 + ty * 4 + (i & 3);
#pragma unroll
    for (int jb = 0; jb < 2; ++jb) {
      const int c = col0 + jb * 64 + tx * 4;
      float4 v;
      v.x = acc[i][jb * 4 + 0];
      v.y = acc[i][jb * 4 + 1];
      v.z = acc[i][jb * 4 + 2];
      v.w = acc[i][jb * 4 + 3];
      *(float4*)&dst[(size_t)r * NMAT + c] = v;
    }
  }
}

// ordered reduction: out = (((0+c0)+c1)+c2)+c3 [+ Addm], one fp32 rounding per
// add — bit-identical to the r11 tot-flush chain + epilogue add.
template <int DO_ADD>
__global__ __launch_bounds__(256) void reduce_k4(
    const float* __restrict__ Pm, const float* __restrict__ Addm,
    float* __restrict__ outp) {
  const size_t NN = (size_t)NMAT * NMAT;
  const size_t i = ((size_t)blockIdx.x * 256 + threadIdx.x) * 4;
  const float4 c0 = *(const float4*)&Pm[i];
  const float4 c1 = *(const float4*)&Pm[i + NN];
  const float4 c2 = *(const float4*)&Pm[i + 2 * NN];
  const float4 c3 = *(const float4*)&Pm[i + 3 * NN];
  float4 v;
  v.x = __fadd_rn(__fadd_rn(__fadd_rn(__fadd_rn(0.0f, c0.x), c1.x), c2.x), c3.x);
  v.y = __fadd_rn(__fadd_rn(__fadd_rn(__fadd_rn(0.0f, c0.y), c1.y), c2.y), c3.y);
  v.z = __fadd_rn(__fadd_rn(__fadd_rn(__fadd_rn(0.0f, c0.z), c1.z), c2.z), c3.z);
  v.w = __fadd_rn(__fadd_rn(__fadd_rn(__fadd_rn(0.0f, c0.w), c1.w), c2.w), c3.w);
  if (DO_ADD) {
    const float4 ad = *(const float4*)&Addm[i];
    v.x = __fadd_rn(v.x, ad.x);
    v.y = __fadd_rn(v.y, ad.y);
    v.z = __fadd_rn(v.z, ad.z);
    v.w = __fadd_rn(v.w, ad.w);
  }
  *(float4*)&outp[i] = v;
}

// ---------- fallback: r11 full-K kernel (used only if ws too small) ----------
constexpr int FM = 128, FN = 128;
constexpr int LDA = FM + 4;
constexpr int LDB = FN + 4;

template <int DO_ADD>
__global__ __launch_bounds__(256) void sgemm512(
    const float* __restrict__ Am, const float* __restrict__ Bm, float* Cm,
    const float* Addm) {
  __shared__ float As[FK][LDA];
  __shared__ float Bs[FK][LDB];
  const int tid = threadIdx.x;
  const int row0 = blockIdx.y * FM;
  const int col0 = blockIdx.x * FN;
  const int ty = tid >> 4;
  const int tx = tid & 15;
  const int ar = tid >> 2;
  const int ac = (tid & 3) * 4;
  const int bk = tid >> 5;
  const int bc = (tid & 31) * 4;

  float tot[8][8] = {};
  float acc[8][8] = {};
  float4 va0, va1, vb0, vb1;

  va0 = *(const float4*)&Am[(size_t)(row0 + ar) * NMAT + ac];
  va1 = *(const float4*)&Am[(size_t)(row0 + ar + 64) * NMAT + ac];
  vb0 = *(const float4*)&Bm[(size_t)bk * NMAT + col0 + bc];
  vb1 = *(const float4*)&Bm[(size_t)(bk + 8) * NMAT + col0 + bc];

  for (int k0 = 0; k0 < NMAT; k0 += FK) {
    __syncthreads();
    As[ac + 0][ar] = va0.x;
    As[ac + 1][ar] = va0.y;
    As[ac + 2][ar] = va0.z;
    As[ac + 3][ar] = va0.w;
    As[ac + 0][ar + 64] = va1.x;
    As[ac + 1][ar + 64] = va1.y;
    As[ac + 2][ar + 64] = va1.z;
    As[ac + 3][ar + 64] = va1.w;
    *(float4*)&Bs[bk][bc] = vb0;
    *(float4*)&Bs[bk + 8][bc] = vb1;
    __syncthreads();

    if (k0 + FK < NMAT) {
      const int kn = k0 + FK;
      va0 = *(const float4*)&Am[(size_t)(row0 + ar) * NMAT + kn + ac];
      va1 = *(const float4*)&Am[(size_t)(row0 + ar + 64) * NMAT + kn + ac];
      vb0 = *(const float4*)&Bm[(size_t)(kn + bk) * NMAT + col0 + bc];
      vb1 = *(const float4*)&Bm[(size_t)(kn + bk + 8) * NMAT + col0 + bc];
    }

#pragma unroll
    for (int k = 0; k < FK; ++k) {
      const float4 a0 = *(const float4*)&As[k][ty * 4];
      const float4 a1 = *(const float4*)&As[k][64 + ty * 4];
      const float4 b0 = *(const float4*)&Bs[k][tx * 4];
      const float4 b1 = *(const float4*)&Bs[k][64 + tx * 4];
      const float af[8] = {a0.x, a0.y, a0.z, a0.w, a1.x, a1.y, a1.z, a1.w};
      const float bf[8] = {b0.x, b0.y, b0.z, b0.w, b1.x, b1.y, b1.z, b1.w};
#pragma unroll
      for (int i = 0; i < 8; ++i)
#pragma unroll
        for (int j = 0; j < 8; ++j)
          acc[i][j] = fmaf(af[i], bf[j], acc[i][j]);
    }

    if (((k0 + FK) & 511) == 0) {
#pragma unroll
      for (int i = 0; i < 8; ++i)
#pragma unroll
        for (int j = 0; j < 8; ++j) {
          tot[i][j] = __fadd_rn(tot[i][j], acc[i][j]);
          acc[i][j] = 0.0f;
        }
    }
  }

#pragma unroll
  for (int i = 0; i < 8; ++i) {
    const int r = row0 + ((i < 4) ? (ty * 4 + i) : (64 + ty * 4 + (i - 4)));
#pragma unroll
    for (int jb = 0; jb < 2; ++jb) {
      const int c = col0 + ((jb == 0) ? (tx * 4) : (64 + tx * 4));
      const size_t idx = (size_t)r * NMAT + c;
      float4 v;
      v.x = tot[i][jb * 4 + 0];
      v.y = tot[i][jb * 4 + 1];
      v.z = tot[i][jb * 4 + 2];
      v.w = tot[i][jb * 4 + 3];
      if (DO_ADD) {
        const float4 ad = *(const float4*)&Addm[idx];
        v.x = __fadd_rn(v.x, ad.x);
        v.y = __fadd_rn(v.y, ad.y);
        v.z = __fadd_rn(v.z, ad.z);
        v.w = __fadd_rn(v.w, ad.w);
      }
      *(float4*)&Cm[idx] = v;
    }
  }
}

// out = t1 - (t2 + t3*t4/t5), each op one fp32 rounding, numpy eval order.
__global__ __launch_bounds__(256) void final_fp32(
    const float* __restrict__ t1, const float* __restrict__ t2,
    const float* t3, const float* __restrict__ t4,
    const float* __restrict__ t5, float* outp) {
  size_t i = (size_t)blockIdx.x * 256 + threadIdx.x;
  float num = __fmul_rn(t3[i], t4[i]);
  float q = __fdiv_rn(num, t5[i]);
  float s = __fadd_rn(t2[i], q);
  outp[i] = __fsub_rn(t1[i], s);
}

extern "C" void kernel_launch(void* const* d_in, const int* in_sizes, int n_in,
                              void* d_out, int out_size, void* d_ws,
                              size_t ws_size, hipStream_t stream) {
  const float* X1 = (const float*)d_in[0];
  const float* X2 = (const float*)d_in[1];
  float* out = (float*)d_out;

  const size_t NN = (size_t)NMAT * NMAT;
  const size_t M32 = NN * sizeof(float); // 16 MiB
  char* w = (char*)d_ws;
  float* fA  = (float*)(w + 0 * M32);
  float* fB  = (float*)(w + 1 * M32);
  float* fC  = (float*)(w + 2 * M32);
  float* fD  = (float*)(w + 3 * M32);
  float* fP  = (float*)(w + 4 * M32);
  float* fQ  = (float*)(w + 5 * M32);
  float* t2f = (float*)(w + 6 * M32);
  float* t4f = (float*)(w + 7 * M32);
  float* fT  = (float*)(w + 2 * M32); // reuse fC slab (dead after t3)
  float* t5f = (float*)(w + 3 * M32); // reuse fD slab (dead after t4)

  dim3 blk(256);
  dim3 ew((unsigned)(NN / 256));

  if (ws_size >= 12 * M32) {
    // split-K path: 12 slabs = 192 MiB (8 named + 4 partial chunks)
    float* Pk = (float*)(w + 8 * M32); // 4 x 16 MiB partials
    dim3 gsk(NMAT / CN, NMAT / CM, 4); // 16 x 8 x 4 = 512 blocks
    dim3 gr((unsigned)(NN / (256 * 4)));

    auto gemm = [&](const float* A, const float* B, float* dst,
                    const float* add) {
      sgemm_chunk<<<gsk, blk, 0, stream>>>(A, B, Pk);
      if (add)
        reduce_k4<1><<<gr, blk, 0, stream>>>(Pk, add, dst);
      else
        reduce_k4<0><<<gr, blk, 0, stream>>>(Pk, nullptr, dst);
    };

    gemm(X1, X1, fA, nullptr);  // A  = X1@X1
    gemm(X1, X2, fB, nullptr);  // B  = X1@X2
    gemm(X2, fB, fC, nullptr);  // C  = X2@B
    gemm(X2, fA, fD, nullptr);  // D  = X2@A
    gemm(fC, fA, fP, nullptr);  // P  = C@A
    gemm(fD, fB, fQ, nullptr);  // Q  = D@B
    gemm(fB, fA, out, fC);      // t3 = B@A + C
    gemm(fD, X2, t4f, fP);      // t4 = D@X2 + P
    gemm(fA, X2, t2f, fB);      // t2 = A@X2 + B
    gemm(fP, fA, fT, nullptr);  // T  = P@A
    gemm(fQ, fA, t5f, fT);      // t5 = Q@A + T
    final_fp32<<<ew, blk, 0, stream>>>(fA, t2f, out, t4f, t5f, out);
  } else {
    // fallback: r11 path (128 MiB ws)
    dim3 grid(NMAT / FN, NMAT / FM);
    sgemm512<0><<<grid, blk, 0, stream>>>(X1, X1, fA, nullptr);
    sgemm512<0><<<grid, blk, 0, stream>>>(X1, X2, fB, nullptr);
    sgemm512<0><<<grid, blk, 0, stream>>>(X2, fB, fC, nullptr);
    sgemm512<0><<<grid, blk, 0, stream>>>(X2, fA, fD, nullptr);
    sgemm512<0><<<grid, blk, 0, stream>>>(fC, fA, fP, nullptr);
    sgemm512<0><<<grid, blk, 0, stream>>>(fD, fB, fQ, nullptr);
    sgemm512<1><<<grid, blk, 0, stream>>>(fB, fA, out, fC);
    sgemm512<1><<<grid, blk, 0, stream>>>(fD, X2, t4f, fP);
    sgemm512<1><<<grid, blk, 0, stream>>>(fA, X2, t2f, fB);
    sgemm512<0><<<grid, blk, 0, stream>>>(fP, fA, fT, nullptr);
    sgemm512<1><<<grid, blk, 0, stream>>>(fQ, fA, t5f, fT);
    final_fp32<<<ew, blk, 0, stream>>>(fA, t2f, out, t4f, t5f, out);
  }
}